// Round 7
// baseline (2146.919 us; speedup 1.0000x reference)
//
#include <hip/hip_runtime.h>

// RecurrentNEFLayer on MI355X — persistent-kernel scan.
// 128 blocks = 8 batch-groups (32 rows) x 16 neuron-groups (128 neurons).
// Weights LDS-resident (bf16); fence-free memory-side protocol (r5, proven).
// r7: (a) s-reduction via global_atomic_pk_add_f16 (2 d-values per 4B RMW,
//     half the transactions of r5's f32 adds; S buffers are f16 now),
//     (b) u-half of GEMM A + u staging hoisted BEFORE the poll (s-independent),
//     (c) per-wave flag post right after explicit vmcnt(0) drain.

constexpr int CB   = 256;   // batch
constexpr int CT   = 512;   // time steps
constexpr int DIN  = 128;
constexpr int DST  = 128;
constexpr int DOUT = 64;
constexpr int DAUG = 256;   // DIN + DST

constexpr int NBG = 8;      // batch groups
constexpr int NNG = 16;     // neuron groups (blocks per barrier group)
constexpr int BT  = 32;     // batch rows per group
constexpr int NT  = 128;    // neurons per block

constexpr int EPAD = 264;   // 256 + 8 bf16 pad (row stride ≡ 4 dwords mod 32 → 2-way, free)
constexpr int APAD = 136;   // 128 + 8 bf16 pad

using f32x4  = __attribute__((ext_vector_type(4))) float;
using bf16x8 = __attribute__((ext_vector_type(8))) short;   // 8 bf16 in 4 VGPRs

__device__ __forceinline__ short f2b(float x) {   // f32 -> bf16 RNE
  unsigned u = __builtin_bit_cast(unsigned, x);
  u += 0x7fffu + ((u >> 16) & 1u);
  return (short)(u >> 16);
}
__device__ __forceinline__ short4 f2b4(float4 v) {
  return make_short4(f2b(v.x), f2b(v.y), f2b(v.z), f2b(v.w));
}
__device__ __forceinline__ float h2f(unsigned short h) {   // f16 bits -> f32
  return (float)__builtin_bit_cast(_Float16, h);
}
__device__ __forceinline__ unsigned pack_h2(float lo, float hi) {  // 2xf16 in u32
  unsigned short l = __builtin_bit_cast(unsigned short, (_Float16)lo);
  unsigned short h = __builtin_bit_cast(unsigned short, (_Float16)hi);
  return (unsigned)l | ((unsigned)h << 16);
}
__device__ __forceinline__ void pk_add_f16(unsigned* addr, unsigned val) {
  asm volatile("global_atomic_pk_add_f16 %0, %1, off"
               :: "v"((unsigned long long)addr), "v"(val) : "memory");
}

__global__ void nef_init(unsigned* Sbuf, unsigned int* ctrs, float* out) {
  int idx = blockIdx.x * blockDim.x + threadIdx.x;
  int stride = gridDim.x * blockDim.x;
  for (int i = idx; i < 4 * CB * 64; i += stride) Sbuf[i] = 0u;   // 4 f16 state bufs
  for (int i = idx; i < CB * DOUT; i += stride) out[i] = 0.f;
  if (idx < 16 * 64) ctrs[idx] = 0u;                              // barrier ctrs
}

__global__ void __launch_bounds__(256) nef_main(
    const float* __restrict__ seq,  const float* __restrict__ enc,
    const float* __restrict__ gainp,const float* __restrict__ biasp,
    const float* __restrict__ sdec, const float* __restrict__ dec,
    float* __restrict__ out, unsigned* __restrict__ Sbuf, unsigned int* ctrs)
{
  __shared__ short E_lds[NT][EPAD];     // encoders tile  [n][k_aug]   67.6 KB
  __shared__ short SDT_lds[DST][APAD];  // state_dec^T    [d][n]       34.8 KB
  __shared__ short X_lds[BT][EPAD];     // [u_t | s_t]    [b][k_aug]   16.9 KB
  __shared__ short A_lds[BT][APAD];     // activations    [b][n]        8.7 KB
  __shared__ float gain_lds[NT];
  __shared__ float bias_lds[NT];

  const int tid  = threadIdx.x;
  const int bg   = blockIdx.x & 7;    // group's 16 blocks spread over XCDs (perf only)
  const int ng   = blockIdx.x >> 3;
  const int b0   = bg * BT;
  const int n0   = ng * NT;
  const int wave = tid >> 6;
  const int lane = tid & 63;
  const int l15  = lane & 15;
  const int lhi  = lane >> 4;         // 0..3
  const int kbase = lhi * 8;

  // ---- one-time: stage weights into LDS (bf16) ----
  for (int i = 0; i < 32; ++i) {                       // encoders: 128x256 f32
    int fidx = i * 256 + tid;
    int row = fidx >> 6, c4 = fidx & 63;
    const float4 v = *(const float4*)(enc + (size_t)(n0 + row) * DAUG + (c4 << 2));
    *(short4*)&E_lds[row][c4 << 2] = f2b4(v);
  }
  for (int i = 0; i < 16; ++i) {                       // state_decoders: transpose
    int fidx = i * 256 + tid;
    int n = fidx >> 5, c4 = fidx & 31;
    const float4 v = *(const float4*)(sdec + (size_t)(n0 + n) * DST + (c4 << 2));
    SDT_lds[(c4 << 2) + 0][n] = f2b(v.x);
    SDT_lds[(c4 << 2) + 1][n] = f2b(v.y);
    SDT_lds[(c4 << 2) + 2][n] = f2b(v.z);
    SDT_lds[(c4 << 2) + 3][n] = f2b(v.w);
  }
  if (tid < NT) { gain_lds[tid] = gainp[n0 + tid]; bias_lds[tid] = biasp[n0 + tid]; }

  unsigned int* ctr = ctrs + bg * 64;   // one 256B-strided ctr per group
  const int nsub0 = wave * 32, nsub1 = nsub0 + 16;

  // ---- prologue: pu = u_0; stage X u-half; prefetch u_1 ----
  float4 pu[4];
#pragma unroll
  for (int i = 0; i < 4; ++i) {
    int fidx = i * 256 + tid;
    int row = fidx >> 5, c4 = fidx & 31;
    pu[i] = *(const float4*)(seq + ((size_t)(b0 + row) * CT + 0) * DIN + (c4 << 2));
  }
#pragma unroll
  for (int i = 0; i < 4; ++i) {
    int fidx = i * 256 + tid;
    int row = fidx >> 5, c4 = fidx & 31;
    *(short4*)&X_lds[row][c4 << 2] = f2b4(pu[i]);
    pu[i] = *(const float4*)(seq + ((size_t)(b0 + row) * CT + 1) * DIN + (c4 << 2));
  }
  __syncthreads();

  for (int t = 0; t < CT; ++t) {
    // ---- zero S[(t+2)&3]: last read at t-2 (proven done: we passed poll(t-1)),
    // next written at t+1 (after our step-t flag) -> safe, fire-and-forget ----
    if (tid < 128) {
      unsigned* Sz = Sbuf + ((t + 2) & 3) * (CB * 64);
      __hip_atomic_store(&Sz[b0 * 64 + ng * 128 + tid], 0u,
                         __ATOMIC_RELAXED, __HIP_MEMORY_SCOPE_AGENT);
    }

    // ---- GEMM A u-half (kk 0..3): s-independent, runs while producers finish ----
    f32x4 acc00 = {0,0,0,0}, acc01 = {0,0,0,0}, acc10 = {0,0,0,0}, acc11 = {0,0,0,0};
#pragma unroll
    for (int kk = 0; kk < 4; ++kk) {
      bf16x8 a0 = *(const bf16x8*)&X_lds[l15][kk * 32 + kbase];
      bf16x8 a1 = *(const bf16x8*)&X_lds[16 + l15][kk * 32 + kbase];
      bf16x8 e0 = *(const bf16x8*)&E_lds[nsub0 + l15][kk * 32 + kbase];
      bf16x8 e1 = *(const bf16x8*)&E_lds[nsub1 + l15][kk * 32 + kbase];
      acc00 = __builtin_amdgcn_mfma_f32_16x16x32_bf16(a0, e0, acc00, 0, 0, 0);
      acc01 = __builtin_amdgcn_mfma_f32_16x16x32_bf16(a0, e1, acc01, 0, 0, 0);
      acc10 = __builtin_amdgcn_mfma_f32_16x16x32_bf16(a1, e0, acc10, 0, 0, 0);
      acc11 = __builtin_amdgcn_mfma_f32_16x16x32_bf16(a1, e1, acc11, 0, 0, 0);
    }

    // ---- wait for s_t: all 16 group blocks (64 waves) posted step t-1 ----
    if (t > 0) {
      unsigned int tgt = 64u * (unsigned)t, guard = 0;
      while (__hip_atomic_load(ctr, __ATOMIC_RELAXED, __HIP_MEMORY_SCOPE_AGENT) < tgt) {
        __builtin_amdgcn_s_sleep(1);
        if (++guard > 100000u) break;   // bounded: wrong answer, never a wedge
      }
    }
    // ---- stage s-half: S f16 (MALL) -> bf16 LDS via 8B agent atomic loads ----
    {
      const unsigned long long* Sr =
          (const unsigned long long*)(Sbuf + (t & 3) * (CB * 64));
#pragma unroll
      for (int i = 0; i < 4; ++i) {
        int idx4 = i * 256 + tid;            // 1024 chunks of 4 f16
        int row = idx4 >> 5, c = idx4 & 31;  // 32 chunks per row
        unsigned long long w = __hip_atomic_load(&Sr[(size_t)(b0 + row) * 32 + c],
                                                 __ATOMIC_RELAXED,
                                                 __HIP_MEMORY_SCOPE_AGENT);
        *(short4*)&X_lds[row][DIN + c * 4] = make_short4(
            f2b(h2f((unsigned short)(w       & 0xffffu))),
            f2b(h2f((unsigned short)((w>>16) & 0xffffu))),
            f2b(h2f((unsigned short)((w>>32) & 0xffffu))),
            f2b(h2f((unsigned short)((w>>48) & 0xffffu))));
      }
    }
    __syncthreads();

    // ---- GEMM A s-half (kk 4..7) ----
#pragma unroll
    for (int kk = 4; kk < 8; ++kk) {
      bf16x8 a0 = *(const bf16x8*)&X_lds[l15][kk * 32 + kbase];
      bf16x8 a1 = *(const bf16x8*)&X_lds[16 + l15][kk * 32 + kbase];
      bf16x8 e0 = *(const bf16x8*)&E_lds[nsub0 + l15][kk * 32 + kbase];
      bf16x8 e1 = *(const bf16x8*)&E_lds[nsub1 + l15][kk * 32 + kbase];
      acc00 = __builtin_amdgcn_mfma_f32_16x16x32_bf16(a0, e0, acc00, 0, 0, 0);
      acc01 = __builtin_amdgcn_mfma_f32_16x16x32_bf16(a0, e1, acc01, 0, 0, 0);
      acc10 = __builtin_amdgcn_mfma_f32_16x16x32_bf16(a1, e0, acc10, 0, 0, 0);
      acc11 = __builtin_amdgcn_mfma_f32_16x16x32_bf16(a1, e1, acc11, 0, 0, 0);
    }
    {   // epilogue: relu(gain*x + bias) -> bf16 a-tile in LDS
      const int nc0 = nsub0 + l15, nc1 = nsub1 + l15;
      const float g0 = gain_lds[nc0], bi0 = bias_lds[nc0];
      const float g1 = gain_lds[nc1], bi1 = bias_lds[nc1];
#pragma unroll
      for (int j = 0; j < 4; ++j) {   // C/D: col=lane&15, row=(lane>>4)*4+j
        A_lds[lhi * 4 + j][nc0]      = f2b(fmaxf(g0 * acc00[j] + bi0, 0.f));
        A_lds[lhi * 4 + j][nc1]      = f2b(fmaxf(g1 * acc01[j] + bi1, 0.f));
        A_lds[16 + lhi * 4 + j][nc0] = f2b(fmaxf(g0 * acc10[j] + bi0, 0.f));
        A_lds[16 + lhi * 4 + j][nc1] = f2b(fmaxf(g1 * acc11[j] + bi1, 0.f));
      }
    }
    __syncthreads();

    if (t != CT - 1) {
      // ---- GEMM B: (32 x 128) @ (128 x 128) -> partial s_{t+1} ----
      f32x4 p00 = {0,0,0,0}, p01 = {0,0,0,0}, p10 = {0,0,0,0}, p11 = {0,0,0,0};
      const int d0 = nsub0 + l15, d1 = nsub1 + l15;
#pragma unroll
      for (int kk = 0; kk < 4; ++kk) {
        bf16x8 a0 = *(const bf16x8*)&A_lds[l15][kk * 32 + kbase];
        bf16x8 a1 = *(const bf16x8*)&A_lds[16 + l15][kk * 32 + kbase];
        bf16x8 s0 = *(const bf16x8*)&SDT_lds[d0][kk * 32 + kbase];
        bf16x8 s1 = *(const bf16x8*)&SDT_lds[d1][kk * 32 + kbase];
        p00 = __builtin_amdgcn_mfma_f32_16x16x32_bf16(a0, s0, p00, 0, 0, 0);
        p01 = __builtin_amdgcn_mfma_f32_16x16x32_bf16(a0, s1, p01, 0, 0, 0);
        p10 = __builtin_amdgcn_mfma_f32_16x16x32_bf16(a1, s0, p10, 0, 0, 0);
        p11 = __builtin_amdgcn_mfma_f32_16x16x32_bf16(a1, s1, p11, 0, 0, 0);
      }
      // ---- pk-f16 atomics: lane pairs pack adjacent d columns (8 RMW/thread) ----
      unsigned* Sw = Sbuf + ((t + 1) & 3) * (CB * 64);
      const bool ev = (l15 & 1) == 0;
      const int colA = ev ? (nsub0 + l15) : (nsub1 + l15 - 1);   // even col of pair
#pragma unroll
      for (int j = 0; j < 4; ++j) {
        float x0 = __shfl_xor(p00[j], 1), x1 = __shfl_xor(p01[j], 1);
        float lo = ev ? p00[j] : x1, hi = ev ? x0 : p01[j];
        pk_add_f16(&Sw[(size_t)(b0 + lhi * 4 + j) * 64 + (colA >> 1)],
                   pack_h2(lo, hi));
        float y0 = __shfl_xor(p10[j], 1), y1 = __shfl_xor(p11[j], 1);
        lo = ev ? p10[j] : y1; hi = ev ? y0 : p11[j];
        pk_add_f16(&Sw[(size_t)(b0 + 16 + lhi * 4 + j) * 64 + (colA >> 1)],
                   pack_h2(lo, hi));
      }
      // ---- per-wave drain + flag post (no block barrier on the post path) ----
      asm volatile("s_waitcnt vmcnt(0)" ::: "memory");
      if (lane == 0) atomicAdd(ctr, 1u);
      // ---- off-path: stage u_{t+1} into X, prefetch u_{t+2} ----
#pragma unroll
      for (int i = 0; i < 4; ++i) {
        int fidx = i * 256 + tid;
        int row = fidx >> 5, c4 = fidx & 31;
        *(short4*)&X_lds[row][c4 << 2] = f2b4(pu[i]);
        if (t + 2 < CT)
          pu[i] = *(const float4*)(seq + ((size_t)(b0 + row) * CT + (t + 2)) * DIN + (c4 << 2));
      }
      __syncthreads();   // X u-half ready for next iter's pre-poll MFMAs
    } else {
      // ---- final step: out partial = a_final @ decoders[n0:n0+128] ----
      f32x4 o0 = {0,0,0,0}, o1 = {0,0,0,0};
      const int ocol = wave * 16 + l15;   // 4 waves x 16 = DOUT
#pragma unroll
      for (int kk = 0; kk < 4; ++kk) {
        bf16x8 a0 = *(const bf16x8*)&A_lds[l15][kk * 32 + kbase];
        bf16x8 a1 = *(const bf16x8*)&A_lds[16 + l15][kk * 32 + kbase];
        bf16x8 bfD;
#pragma unroll
        for (int j = 0; j < 8; ++j)
          bfD[j] = f2b(dec[(size_t)(n0 + kk * 32 + kbase + j) * DOUT + ocol]);
        o0 = __builtin_amdgcn_mfma_f32_16x16x32_bf16(a0, bfD, o0, 0, 0, 0);
        o1 = __builtin_amdgcn_mfma_f32_16x16x32_bf16(a1, bfD, o1, 0, 0, 0);
      }
#pragma unroll
      for (int j = 0; j < 4; ++j) {       // one-time 16-way K-split reduction (f32)
        unsafeAtomicAdd(&out[(size_t)(b0 + lhi * 4 + j) * DOUT + ocol], o0[j]);
        unsafeAtomicAdd(&out[(size_t)(b0 + 16 + lhi * 4 + j) * DOUT + ocol], o1[j]);
      }
    }
  }
}

extern "C" void kernel_launch(void* const* d_in, const int* in_sizes, int n_in,
                              void* d_out, int out_size, void* d_ws, size_t ws_size,
                              hipStream_t stream) {
  const float* seq   = (const float*)d_in[0];
  const float* enc   = (const float*)d_in[1];
  const float* gainp = (const float*)d_in[2];
  const float* biasp = (const float*)d_in[3];
  const float* sdec  = (const float*)d_in[4];
  const float* dec   = (const float*)d_in[5];
  float* out = (float*)d_out;

  // workspace: Sbuf f16 [4][256][128] = 256 KB | ctrs 4 KB
  unsigned* Sbuf = (unsigned*)d_ws;
  unsigned int* ctrs = (unsigned int*)((char*)d_ws + (size_t)4 * CB * 64 * sizeof(unsigned));

  nef_init<<<128, 256, 0, stream>>>(Sbuf, ctrs, out);
  nef_main<<<dim3(NBG * NNG), dim3(256), 0, stream>>>(seq, enc, gainp, biasp,
                                                      sdec, dec, out, Sbuf, ctrs);
}

// Round 8
// 2097.846 us; speedup vs baseline: 1.0234x; 1.0234x over previous
//
#include <hip/hip_runtime.h>

// RecurrentNEFLayer on MI355X — persistent-kernel scan, dual phase-shifted chains.
// 128 blocks = 8 k-slots x 16 neuron-groups; each block serves TWO independent
// batch-groups (chains) of 16 rows: chain A = group 2k, chain B = group 2k+1.
// While chain A's communication (atomic drain -> flag -> sibling poll -> s read,
// ~2.3us of pure MALL latency in r6) propagates, the block computes chain B's
// step, and vice versa. Protocol per chain is r6's proven fence-free scheme:
//  - s_{t+1} via unsafeAtomicAdd f32 (memory-side LLC RMW, no CAS loop)
//  - one flag atomicAdd per block per chain-step (16 posts/step; r7 showed
//    64 posts/step costs ~+0.8us in same-line RMW serialization)
//  - S staged via relaxed agent atomic loads; zeroed via relaxed agent stores
//  - 4-buffer rotation, zero S[(t+2)&3] (safe: passed poll(t-1) for both chains)

constexpr int CB   = 256;   // batch
constexpr int CT   = 512;   // time steps
constexpr int DIN  = 128;
constexpr int DST  = 128;
constexpr int DOUT = 64;
constexpr int DAUG = 256;   // DIN + DST

constexpr int NBG = 16;     // batch groups (chains), 16 rows each
constexpr int NNG = 16;     // neuron groups (blocks per chain barrier group)
constexpr int BT  = 16;     // batch rows per chain
constexpr int NT  = 128;    // neurons per block

constexpr int EPAD = 264;   // 256 + 8 bf16 pad (keeps 16B row alignment for b128)
constexpr int APAD = 136;   // 128 + 8 bf16 pad

using f32x4  = __attribute__((ext_vector_type(4))) float;
using bf16x8 = __attribute__((ext_vector_type(8))) short;   // 8 bf16 in 4 VGPRs

__device__ __forceinline__ short f2b(float x) {   // f32 -> bf16 RNE
  unsigned u = __builtin_bit_cast(unsigned, x);
  u += 0x7fffu + ((u >> 16) & 1u);
  return (short)(u >> 16);
}
__device__ __forceinline__ short4 f2b4(float4 v) {
  return make_short4(f2b(v.x), f2b(v.y), f2b(v.z), f2b(v.w));
}

__global__ void nef_init(float* Sbuf, unsigned int* ctrs, float* out) {
  int idx = blockIdx.x * blockDim.x + threadIdx.x;
  int stride = gridDim.x * blockDim.x;
  for (int i = idx; i < 4 * CB * DST; i += stride) Sbuf[i] = 0.f;  // 4 state bufs
  for (int i = idx; i < CB * DOUT; i += stride) out[i] = 0.f;
  if (idx < NBG * 64) ctrs[idx] = 0u;                              // barrier ctrs
}

__global__ void __launch_bounds__(256) nef_main(
    const float* __restrict__ seq,  const float* __restrict__ enc,
    const float* __restrict__ gainp,const float* __restrict__ biasp,
    const float* __restrict__ sdec, const float* __restrict__ dec,
    float* __restrict__ out, float* __restrict__ Sbuf, unsigned int* ctrs)
{
  __shared__ short E_lds[NT][EPAD];       // encoders tile  [n][k_aug]   67.6 KB
  __shared__ short SDT_lds[DST][APAD];    // state_dec^T    [d][n]       34.8 KB
  __shared__ short X_lds[2][BT][EPAD];    // per-chain [u_t | s_t]       16.9 KB
  __shared__ short A_lds[2][BT][APAD];    // per-chain activations        8.7 KB
  __shared__ float gain_lds[NT];
  __shared__ float bias_lds[NT];

  const int tid  = threadIdx.x;
  const int kslot= blockIdx.x & 7;
  const int ng   = blockIdx.x >> 3;
  const int bgA  = 2 * kslot,      bgB = 2 * kslot + 1;
  const int b0A  = bgA * BT,       b0B = bgB * BT;
  const int n0   = ng * NT;
  const int wave = tid >> 6;
  const int lane = tid & 63;
  const int l15  = lane & 15;
  const int lhi  = lane >> 4;         // 0..3
  const int kbase = lhi * 8;

  // ---- one-time: stage weights into LDS (bf16) ----
  for (int i = 0; i < 32; ++i) {                       // encoders: 128x256 f32
    int fidx = i * 256 + tid;
    int row = fidx >> 6, c4 = fidx & 63;
    const float4 v = *(const float4*)(enc + (size_t)(n0 + row) * DAUG + (c4 << 2));
    *(short4*)&E_lds[row][c4 << 2] = f2b4(v);
  }
  for (int i = 0; i < 16; ++i) {                       // state_decoders: transpose
    int fidx = i * 256 + tid;
    int n = fidx >> 5, c4 = fidx & 31;
    const float4 v = *(const float4*)(sdec + (size_t)(n0 + n) * DST + (c4 << 2));
    SDT_lds[(c4 << 2) + 0][n] = f2b(v.x);
    SDT_lds[(c4 << 2) + 1][n] = f2b(v.y);
    SDT_lds[(c4 << 2) + 2][n] = f2b(v.z);
    SDT_lds[(c4 << 2) + 3][n] = f2b(v.w);
  }
  if (tid < NT) { gain_lds[tid] = gainp[n0 + tid]; bias_lds[tid] = biasp[n0 + tid]; }

  unsigned int* ctrA = ctrs + bgA * 64;   // 256B-strided ctr per chain group
  unsigned int* ctrB = ctrs + bgB * 64;
  const int nsub0 = wave * 32, nsub1 = nsub0 + 16;

  // ---- prologue: stage u_0 for both chains; prefetch u_1 ----
  float4 puA[2], puB[2];
#pragma unroll
  for (int i = 0; i < 2; ++i) {
    int fidx = i * 256 + tid;
    int row = fidx >> 5, c4 = fidx & 31;
    puA[i] = *(const float4*)(seq + ((size_t)(b0A + row) * CT + 0) * DIN + (c4 << 2));
    puB[i] = *(const float4*)(seq + ((size_t)(b0B + row) * CT + 0) * DIN + (c4 << 2));
  }
#pragma unroll
  for (int i = 0; i < 2; ++i) {
    int fidx = i * 256 + tid;
    int row = fidx >> 5, c4 = fidx & 31;
    *(short4*)&X_lds[0][row][c4 << 2] = f2b4(puA[i]);
    *(short4*)&X_lds[1][row][c4 << 2] = f2b4(puB[i]);
    puA[i] = *(const float4*)(seq + ((size_t)(b0A + row) * CT + 1) * DIN + (c4 << 2));
    puB[i] = *(const float4*)(seq + ((size_t)(b0B + row) * CT + 1) * DIN + (c4 << 2));
  }
  __syncthreads();

  for (int t = 0; t < CT; ++t) {
    // ---- zero S[(t+2)&3] for both chains (relaxed agent stores, fire-forget).
    // Safe: passed poll(t-1) for both chains -> all siblings done reading it at
    // t-2; next adds to it happen at t+1, after our step-t flags. ----
    {
      float* Sz = Sbuf + ((t + 2) & 3) * (CB * DST);
      int c = tid >> 7;                       // 0: chain A, 1: chain B
      int b0c = c ? b0B : b0A;
      __hip_atomic_store(&Sz[(size_t)b0c * DST + ng * 128 + (tid & 127)], 0.f,
                         __ATOMIC_RELAXED, __HIP_MEMORY_SCOPE_AGENT);
    }

#pragma unroll
    for (int c = 0; c < 2; ++c) {
      const int b0c = c ? b0B : b0A;
      unsigned int* ctr = c ? ctrB : ctrA;

      // ---- wait for this chain's s_t ----
      if (t > 0) {
        unsigned int tgt = 16u * (unsigned)t, guard = 0;
        while (__hip_atomic_load(ctr, __ATOMIC_RELAXED, __HIP_MEMORY_SCOPE_AGENT) < tgt) {
          __builtin_amdgcn_s_sleep(1);
          if (++guard > 100000u) break;   // bounded: wrong answer, never a wedge
        }
      }
      // ---- stage s-half: S f32 (MALL) -> bf16 LDS via 8B agent atomic loads ----
      {
        const float* Sr = Sbuf + (t & 3) * (CB * DST);
        int row = tid >> 4, c8 = tid & 15;       // 16 rows x 16 chunks of 8 f32
        const unsigned long long* p =
            (const unsigned long long*)(Sr + (size_t)(b0c + row) * DST + c8 * 8);
        short s8[8];
#pragma unroll
        for (int q = 0; q < 4; ++q) {
          unsigned long long w = __hip_atomic_load(p + q, __ATOMIC_RELAXED,
                                                   __HIP_MEMORY_SCOPE_AGENT);
          s8[2 * q]     = f2b(__builtin_bit_cast(float, (unsigned)(w & 0xffffffffu)));
          s8[2 * q + 1] = f2b(__builtin_bit_cast(float, (unsigned)(w >> 32)));
        }
        *(short4*)&X_lds[c][row][DIN + c8 * 8]     = make_short4(s8[0], s8[1], s8[2], s8[3]);
        *(short4*)&X_lds[c][row][DIN + c8 * 8 + 4] = make_short4(s8[4], s8[5], s8[6], s8[7]);
      }
      __syncthreads();

      // ---- GEMM A: (16 x 256) @ (256 x 128); wave: 1 m-tile x 2 n-tiles ----
      f32x4 acc0 = {0,0,0,0}, acc1 = {0,0,0,0};
#pragma unroll
      for (int kk = 0; kk < 8; ++kk) {
        bf16x8 a0 = *(const bf16x8*)&X_lds[c][l15][kk * 32 + kbase];
        bf16x8 e0 = *(const bf16x8*)&E_lds[nsub0 + l15][kk * 32 + kbase];
        bf16x8 e1 = *(const bf16x8*)&E_lds[nsub1 + l15][kk * 32 + kbase];
        acc0 = __builtin_amdgcn_mfma_f32_16x16x32_bf16(a0, e0, acc0, 0, 0, 0);
        acc1 = __builtin_amdgcn_mfma_f32_16x16x32_bf16(a0, e1, acc1, 0, 0, 0);
      }
      {   // epilogue: relu(gain*x + bias) -> bf16 a-tile in LDS
        const int nc0 = nsub0 + l15, nc1 = nsub1 + l15;
        const float g0 = gain_lds[nc0], bi0 = bias_lds[nc0];
        const float g1 = gain_lds[nc1], bi1 = bias_lds[nc1];
#pragma unroll
        for (int j = 0; j < 4; ++j) {   // C/D: col=lane&15, row=(lane>>4)*4+j
          A_lds[c][lhi * 4 + j][nc0] = f2b(fmaxf(g0 * acc0[j] + bi0, 0.f));
          A_lds[c][lhi * 4 + j][nc1] = f2b(fmaxf(g1 * acc1[j] + bi1, 0.f));
        }
      }
      __syncthreads();

      if (t != CT - 1) {
        // ---- GEMM B: (16 x 128) @ (128 x 128) -> partial s_{t+1} ----
        f32x4 p0 = {0,0,0,0}, p1 = {0,0,0,0};
        const int d0 = nsub0 + l15, d1 = nsub1 + l15;
#pragma unroll
        for (int kk = 0; kk < 4; ++kk) {
          bf16x8 a0 = *(const bf16x8*)&A_lds[c][l15][kk * 32 + kbase];
          bf16x8 s0 = *(const bf16x8*)&SDT_lds[d0][kk * 32 + kbase];
          bf16x8 s1 = *(const bf16x8*)&SDT_lds[d1][kk * 32 + kbase];
          p0 = __builtin_amdgcn_mfma_f32_16x16x32_bf16(a0, s0, p0, 0, 0, 0);
          p1 = __builtin_amdgcn_mfma_f32_16x16x32_bf16(a0, s1, p1, 0, 0, 0);
        }
        // ---- memory-side f32 RMWs into S[(t+1)&3] ----
        float* Sw = Sbuf + ((t + 1) & 3) * (CB * DST);
#pragma unroll
        for (int j = 0; j < 4; ++j) {
          unsafeAtomicAdd(&Sw[(size_t)(b0c + lhi * 4 + j) * DST + d0], p0[j]);
          unsafeAtomicAdd(&Sw[(size_t)(b0c + lhi * 4 + j) * DST + d1], p1[j]);
        }
        // ---- stage u_{t+1} into X[c] (DS-only, runs under the atomic drain),
        //      then prefetch u_{t+2} ----
#pragma unroll
        for (int i = 0; i < 2; ++i) {
          int fidx = i * 256 + tid;
          int row = fidx >> 5, c4 = fidx & 31;
          float4* pu = c ? puB : puA;
          *(short4*)&X_lds[c][row][c4 << 2] = f2b4(pu[i]);
          if (t + 2 < CT)
            pu[i] = *(const float4*)(seq + ((size_t)(b0c + row) * CT + (t + 2)) * DIN + (c4 << 2));
        }
        // ---- drain (syncthreads waits vmcnt(0)) + single block flag ----
        __syncthreads();
        if (tid == 0) atomicAdd(ctr, 1u);
      } else {
        // ---- final step: out partial = a_final @ decoders[n0:n0+128] ----
        f32x4 o0 = {0,0,0,0};
        const int ocol = wave * 16 + l15;   // 4 waves x 16 = DOUT
#pragma unroll
        for (int kk = 0; kk < 4; ++kk) {
          bf16x8 a0 = *(const bf16x8*)&A_lds[c][l15][kk * 32 + kbase];
          bf16x8 bfD;
#pragma unroll
          for (int j = 0; j < 8; ++j)
            bfD[j] = f2b(dec[(size_t)(n0 + kk * 32 + kbase + j) * DOUT + ocol]);
          o0 = __builtin_amdgcn_mfma_f32_16x16x32_bf16(a0, bfD, o0, 0, 0, 0);
        }
#pragma unroll
        for (int j = 0; j < 4; ++j)        // one-time 16-way K-split reduction
          unsafeAtomicAdd(&out[(size_t)(b0c + lhi * 4 + j) * DOUT + ocol], o0[j]);
        __syncthreads();   // keep chain phases aligned on the last iteration
      }
    }
  }
}

extern "C" void kernel_launch(void* const* d_in, const int* in_sizes, int n_in,
                              void* d_out, int out_size, void* d_ws, size_t ws_size,
                              hipStream_t stream) {
  const float* seq   = (const float*)d_in[0];
  const float* enc   = (const float*)d_in[1];
  const float* gainp = (const float*)d_in[2];
  const float* biasp = (const float*)d_in[3];
  const float* sdec  = (const float*)d_in[4];
  const float* dec   = (const float*)d_in[5];
  float* out = (float*)d_out;

  // workspace: Sbuf f32 [4][256][128] = 512 KB | ctrs 16*64 u32 = 4 KB
  float* Sbuf = (float*)d_ws;
  unsigned int* ctrs = (unsigned int*)((char*)d_ws + (size_t)4 * CB * DST * sizeof(float));

  nef_init<<<128, 256, 0, stream>>>(Sbuf, ctrs, out);
  nef_main<<<dim3(8 * NNG), dim3(256), 0, stream>>>(seq, enc, gainp, biasp,
                                                    sdec, dec, out, Sbuf, ctrs);
}

// Round 10
// 1698.390 us; speedup vs baseline: 1.2641x; 1.2352x over previous
//
#include <hip/hip_runtime.h>

// RecurrentNEFLayer on MI355X — persistent-kernel scan.
// 128 blocks = 8 batch-groups (32 rows) x 16 neuron-groups (128 neurons).
// Weights LDS-resident (bf16); fence-free memory-side protocol (r6, proven:
// 1673us). r9 = r6 + two scheduling moves, protocol untouched (resubmitted
// unchanged after an infra-failed round — kernel never ran):
//  (1) u-half of GEMM A (kk 0..3) hoisted BEFORE the poll (s-independent),
//  (2) flag posted right after the atomics-drain barrier; u-stage + u_{t+2}
//      prefetch moved AFTER the post (r6 drained the prefetch before the flag,
//      putting an HBM round trip on every step's critical path).

constexpr int CB   = 256;   // batch
constexpr int CT   = 512;   // time steps
constexpr int DIN  = 128;
constexpr int DST  = 128;
constexpr int DOUT = 64;
constexpr int DAUG = 256;   // DIN + DST

constexpr int NBG = 8;      // batch groups
constexpr int NNG = 16;     // neuron groups (blocks per barrier group)
constexpr int BT  = 32;     // batch rows per group
constexpr int NT  = 128;    // neurons per block

constexpr int EPAD = 264;   // 256 + 8 bf16 pad (row stride ≡ 4 dwords mod 32 → 2-way, free)
constexpr int APAD = 136;   // 128 + 8 bf16 pad

using f32x4  = __attribute__((ext_vector_type(4))) float;
using bf16x8 = __attribute__((ext_vector_type(8))) short;   // 8 bf16 in 4 VGPRs

__device__ __forceinline__ short f2b(float x) {   // f32 -> bf16 RNE
  unsigned u = __builtin_bit_cast(unsigned, x);
  u += 0x7fffu + ((u >> 16) & 1u);
  return (short)(u >> 16);
}
__device__ __forceinline__ short4 f2b4(float4 v) {
  return make_short4(f2b(v.x), f2b(v.y), f2b(v.z), f2b(v.w));
}

__global__ void nef_init(float* Sbuf, unsigned int* ctrs, float* out) {
  int idx = blockIdx.x * blockDim.x + threadIdx.x;
  int stride = gridDim.x * blockDim.x;
  for (int i = idx; i < 4 * CB * DST; i += stride) Sbuf[i] = 0.f;  // 4 state buffers
  for (int i = idx; i < CB * DOUT; i += stride) out[i] = 0.f;
  if (idx < 16 * 64) ctrs[idx] = 0u;                               // barrier ctrs
}

__global__ void __launch_bounds__(256) nef_main(
    const float* __restrict__ seq,  const float* __restrict__ enc,
    const float* __restrict__ gainp,const float* __restrict__ biasp,
    const float* __restrict__ sdec, const float* __restrict__ dec,
    float* __restrict__ out, float* __restrict__ Sbuf, unsigned int* ctrs)
{
  __shared__ short E_lds[NT][EPAD];     // encoders tile  [n][k_aug]   67.6 KB
  __shared__ short SDT_lds[DST][APAD];  // state_dec^T    [d][n]       34.8 KB
  __shared__ short X_lds[BT][EPAD];     // [u_t | s_t]    [b][k_aug]   16.9 KB
  __shared__ short A_lds[BT][APAD];     // activations    [b][n]        8.7 KB
  __shared__ float gain_lds[NT];
  __shared__ float bias_lds[NT];

  const int tid  = threadIdx.x;
  const int bg   = blockIdx.x & 7;    // group's 16 blocks spread over XCDs (perf only)
  const int ng   = blockIdx.x >> 3;
  const int b0   = bg * BT;
  const int n0   = ng * NT;
  const int wave = tid >> 6;
  const int lane = tid & 63;
  const int l15  = lane & 15;
  const int lhi  = lane >> 4;         // 0..3
  const int kbase = lhi * 8;

  // ---- one-time: stage weights into LDS (bf16) ----
  for (int i = 0; i < 32; ++i) {                       // encoders: 128x256 f32
    int fidx = i * 256 + tid;
    int row = fidx >> 6, c4 = fidx & 63;
    const float4 v = *(const float4*)(enc + (size_t)(n0 + row) * DAUG + (c4 << 2));
    *(short4*)&E_lds[row][c4 << 2] = f2b4(v);
  }
  for (int i = 0; i < 16; ++i) {                       // state_decoders: transpose
    int fidx = i * 256 + tid;
    int n = fidx >> 5, c4 = fidx & 31;
    const float4 v = *(const float4*)(sdec + (size_t)(n0 + n) * DST + (c4 << 2));
    SDT_lds[(c4 << 2) + 0][n] = f2b(v.x);
    SDT_lds[(c4 << 2) + 1][n] = f2b(v.y);
    SDT_lds[(c4 << 2) + 2][n] = f2b(v.z);
    SDT_lds[(c4 << 2) + 3][n] = f2b(v.w);
  }
  if (tid < NT) { gain_lds[tid] = gainp[n0 + tid]; bias_lds[tid] = biasp[n0 + tid]; }

  unsigned int* ctr = ctrs + bg * 64;   // one 256B-strided ctr per group
  const int nsub0 = wave * 32, nsub1 = nsub0 + 16;

  // ---- prologue: load u_0, stage X u-half, prefetch u_1 ----
  float4 pu[4];
#pragma unroll
  for (int i = 0; i < 4; ++i) {
    int fidx = i * 256 + tid;
    int row = fidx >> 5, c4 = fidx & 31;
    pu[i] = *(const float4*)(seq + ((size_t)(b0 + row) * CT + 0) * DIN + (c4 << 2));
  }
#pragma unroll
  for (int i = 0; i < 4; ++i) {
    int fidx = i * 256 + tid;
    int row = fidx >> 5, c4 = fidx & 31;
    *(short4*)&X_lds[row][c4 << 2] = f2b4(pu[i]);
    pu[i] = *(const float4*)(seq + ((size_t)(b0 + row) * CT + 1) * DIN + (c4 << 2));
  }
  __syncthreads();   // weights + u_0 staged

  for (int t = 0; t < CT; ++t) {
    // ---- zero S[(t+2)&3] (fire-forget agent stores; drained at the first
    // barrier below, well before this step's flag — so ordering vs the t+1
    // adders, who are gated on our flag(t), is guaranteed). Safety of target
    // choice: its readers ran at t-2 (we passed poll(t-1)); next adds at t+1.
    {
      float* Sz = Sbuf + ((t + 2) & 3) * (CB * DST);
      __hip_atomic_store(&Sz[b0 * DST + ng * 256 + tid], 0.f,
                         __ATOMIC_RELAXED, __HIP_MEMORY_SCOPE_AGENT);
    }

    // ---- GEMM A u-half (kk 0..3): s-independent, runs while producers finish ----
    f32x4 acc00 = {0,0,0,0}, acc01 = {0,0,0,0}, acc10 = {0,0,0,0}, acc11 = {0,0,0,0};
#pragma unroll
    for (int kk = 0; kk < 4; ++kk) {
      bf16x8 a0 = *(const bf16x8*)&X_lds[l15][kk * 32 + kbase];
      bf16x8 a1 = *(const bf16x8*)&X_lds[16 + l15][kk * 32 + kbase];
      bf16x8 e0 = *(const bf16x8*)&E_lds[nsub0 + l15][kk * 32 + kbase];
      bf16x8 e1 = *(const bf16x8*)&E_lds[nsub1 + l15][kk * 32 + kbase];
      acc00 = __builtin_amdgcn_mfma_f32_16x16x32_bf16(a0, e0, acc00, 0, 0, 0);
      acc01 = __builtin_amdgcn_mfma_f32_16x16x32_bf16(a0, e1, acc01, 0, 0, 0);
      acc10 = __builtin_amdgcn_mfma_f32_16x16x32_bf16(a1, e0, acc10, 0, 0, 0);
      acc11 = __builtin_amdgcn_mfma_f32_16x16x32_bf16(a1, e1, acc11, 0, 0, 0);
    }

    // ---- wait for s_t: all 16 group blocks posted step t-1 adds ----
    if (t > 0) {
      unsigned int tgt = 16u * (unsigned)t, guard = 0;
      while (__hip_atomic_load(ctr, __ATOMIC_RELAXED, __HIP_MEMORY_SCOPE_AGENT) < tgt) {
        __builtin_amdgcn_s_sleep(1);
        if (++guard > 100000u) break;   // bounded: wrong answer, never a wedge
      }
    }
    // ---- stage s-half: S f32 (MALL) -> bf16 LDS via 8B agent atomic loads ----
    {
      const float* Sr = Sbuf + (t & 3) * (CB * DST);
#pragma unroll
      for (int i = 0; i < 2; ++i) {
        int idx8 = i * 256 + tid;            // 512 chunks of 8 f32
        int row = idx8 >> 4, c8 = idx8 & 15;
        const unsigned long long* p =
            (const unsigned long long*)(Sr + (size_t)(b0 + row) * DST + c8 * 8);
        short s8[8];
#pragma unroll
        for (int q = 0; q < 4; ++q) {
          unsigned long long w = __hip_atomic_load(p + q, __ATOMIC_RELAXED,
                                                   __HIP_MEMORY_SCOPE_AGENT);
          s8[2 * q]     = f2b(__builtin_bit_cast(float, (unsigned)(w & 0xffffffffu)));
          s8[2 * q + 1] = f2b(__builtin_bit_cast(float, (unsigned)(w >> 32)));
        }
        *(short4*)&X_lds[row][DIN + c8 * 8]     = make_short4(s8[0], s8[1], s8[2], s8[3]);
        *(short4*)&X_lds[row][DIN + c8 * 8 + 4] = make_short4(s8[4], s8[5], s8[6], s8[7]);
      }
    }
    __syncthreads();

    // ---- GEMM A s-half (kk 4..7) ----
#pragma unroll
    for (int kk = 4; kk < 8; ++kk) {
      bf16x8 a0 = *(const bf16x8*)&X_lds[l15][kk * 32 + kbase];
      bf16x8 a1 = *(const bf16x8*)&X_lds[16 + l15][kk * 32 + kbase];
      bf16x8 e0 = *(const bf16x8*)&E_lds[nsub0 + l15][kk * 32 + kbase];
      bf16x8 e1 = *(const bf16x8*)&E_lds[nsub1 + l15][kk * 32 + kbase];
      acc00 = __builtin_amdgcn_mfma_f32_16x16x32_bf16(a0, e0, acc00, 0, 0, 0);
      acc01 = __builtin_amdgcn_mfma_f32_16x16x32_bf16(a0, e1, acc01, 0, 0, 0);
      acc10 = __builtin_amdgcn_mfma_f32_16x16x32_bf16(a1, e0, acc10, 0, 0, 0);
      acc11 = __builtin_amdgcn_mfma_f32_16x16x32_bf16(a1, e1, acc11, 0, 0, 0);
    }
    {   // epilogue: relu(gain*x + bias) -> bf16 a-tile in LDS
      const int nc0 = nsub0 + l15, nc1 = nsub1 + l15;
      const float g0 = gain_lds[nc0], bi0 = bias_lds[nc0];
      const float g1 = gain_lds[nc1], bi1 = bias_lds[nc1];
#pragma unroll
      for (int j = 0; j < 4; ++j) {   // C/D: col=lane&15, row=(lane>>4)*4+j
        A_lds[lhi * 4 + j][nc0]      = f2b(fmaxf(g0 * acc00[j] + bi0, 0.f));
        A_lds[lhi * 4 + j][nc1]      = f2b(fmaxf(g1 * acc01[j] + bi1, 0.f));
        A_lds[16 + lhi * 4 + j][nc0] = f2b(fmaxf(g0 * acc10[j] + bi0, 0.f));
        A_lds[16 + lhi * 4 + j][nc1] = f2b(fmaxf(g1 * acc11[j] + bi1, 0.f));
      }
    }
    __syncthreads();

    if (t != CT - 1) {
      // ---- GEMM B: (32 x 128) @ (128 x 128) -> partial s_{t+1} ----
      f32x4 p00 = {0,0,0,0}, p01 = {0,0,0,0}, p10 = {0,0,0,0}, p11 = {0,0,0,0};
      const int d0 = nsub0 + l15, d1 = nsub1 + l15;
#pragma unroll
      for (int kk = 0; kk < 4; ++kk) {
        bf16x8 a0 = *(const bf16x8*)&A_lds[l15][kk * 32 + kbase];
        bf16x8 a1 = *(const bf16x8*)&A_lds[16 + l15][kk * 32 + kbase];
        bf16x8 s0 = *(const bf16x8*)&SDT_lds[d0][kk * 32 + kbase];
        bf16x8 s1 = *(const bf16x8*)&SDT_lds[d1][kk * 32 + kbase];
        p00 = __builtin_amdgcn_mfma_f32_16x16x32_bf16(a0, s0, p00, 0, 0, 0);
        p01 = __builtin_amdgcn_mfma_f32_16x16x32_bf16(a0, s1, p01, 0, 0, 0);
        p10 = __builtin_amdgcn_mfma_f32_16x16x32_bf16(a1, s0, p10, 0, 0, 0);
        p11 = __builtin_amdgcn_mfma_f32_16x16x32_bf16(a1, s1, p11, 0, 0, 0);
      }
      // ---- memory-side f32 RMWs into S[(t+1)&3] (HW fadd, no CAS loop) ----
      float* Sw = Sbuf + ((t + 1) & 3) * (CB * DST);
#pragma unroll
      for (int j = 0; j < 4; ++j) {
        unsafeAtomicAdd(&Sw[(size_t)(b0 + lhi * 4 + j) * DST + d0],      p00[j]);
        unsafeAtomicAdd(&Sw[(size_t)(b0 + lhi * 4 + j) * DST + d1],      p01[j]);
        unsafeAtomicAdd(&Sw[(size_t)(b0 + 16 + lhi * 4 + j) * DST + d0], p10[j]);
        unsafeAtomicAdd(&Sw[(size_t)(b0 + 16 + lhi * 4 + j) * DST + d1], p11[j]);
      }
      // ---- drain (barrier implies vmcnt(0): atomics + zero-stores only —
      // NO prefetch outstanding here, unlike r6) then post the flag ----
      __syncthreads();
      if (tid == 0) atomicAdd(ctr, 1u);
      // ---- off-path tail: stage u_{t+1} into X, prefetch u_{t+2} ----
#pragma unroll
      for (int i = 0; i < 4; ++i) {
        int fidx = i * 256 + tid;
        int row = fidx >> 5, c4 = fidx & 31;
        *(short4*)&X_lds[row][c4 << 2] = f2b4(pu[i]);
        if (t + 2 < CT)
          pu[i] = *(const float4*)(seq + ((size_t)(b0 + row) * CT + (t + 2)) * DIN + (c4 << 2));
      }
      __syncthreads();   // X u-half ready for next iter's pre-poll MFMAs
    } else {
      // ---- final step: out partial = a_final @ decoders[n0:n0+128] ----
      f32x4 o0 = {0,0,0,0}, o1 = {0,0,0,0};
      const int ocol = wave * 16 + l15;   // 4 waves x 16 = DOUT
#pragma unroll
      for (int kk = 0; kk < 4; ++kk) {
        bf16x8 a0 = *(const bf16x8*)&A_lds[l15][kk * 32 + kbase];
        bf16x8 a1 = *(const bf16x8*)&A_lds[16 + l15][kk * 32 + kbase];
        bf16x8 bfD;
#pragma unroll
        for (int j = 0; j < 8; ++j)
          bfD[j] = f2b(dec[(size_t)(n0 + kk * 32 + kbase + j) * DOUT + ocol]);
        o0 = __builtin_amdgcn_mfma_f32_16x16x32_bf16(a0, bfD, o0, 0, 0, 0);
        o1 = __builtin_amdgcn_mfma_f32_16x16x32_bf16(a1, bfD, o1, 0, 0, 0);
      }
#pragma unroll
      for (int j = 0; j < 4; ++j) {       // one-time 16-way K-split reduction (f32)
        unsafeAtomicAdd(&out[(size_t)(b0 + lhi * 4 + j) * DOUT + ocol], o0[j]);
        unsafeAtomicAdd(&out[(size_t)(b0 + 16 + lhi * 4 + j) * DOUT + ocol], o1[j]);
      }
    }
  }
}

extern "C" void kernel_launch(void* const* d_in, const int* in_sizes, int n_in,
                              void* d_out, int out_size, void* d_ws, size_t ws_size,
                              hipStream_t stream) {
  const float* seq   = (const float*)d_in[0];
  const float* enc   = (const float*)d_in[1];
  const float* gainp = (const float*)d_in[2];
  const float* biasp = (const float*)d_in[3];
  const float* sdec  = (const float*)d_in[4];
  const float* dec   = (const float*)d_in[5];
  float* out = (float*)d_out;

  // workspace: Sbuf f32 [4][256][128] = 512 KB | ctrs 4 KB
  float* Sbuf = (float*)d_ws;
  unsigned int* ctrs = (unsigned int*)((char*)d_ws + (size_t)4 * CB * DST * sizeof(float));

  nef_init<<<128, 256, 0, stream>>>(Sbuf, ctrs, out);
  nef_main<<<dim3(NBG * NNG), dim3(256), 0, stream>>>(seq, enc, gainp, biasp,
                                                      sdec, dec, out, Sbuf, ctrs);
}

// Round 11
// 1505.410 us; speedup vs baseline: 1.4261x; 1.1282x over previous
//
#include <hip/hip_runtime.h>

// RecurrentNEFLayer on MI355X — persistent-kernel scan.
// r11: 128 blocks = 16 batch-groups (16 rows) x 8 neuron-groups (256 neurons).
// Halves the atomic-RMW count per step (262K vs 524K): theory says the step
// floor is memory-side RMW throughput (~60/cy chip-wide; r6=160K RMW/us,
// r8=128K RMW/us both saturate it). Encoders (256x256) LDS-resident bf16;
// state_decoders held in REGISTERS (16 bf16x8 frags/wave) to fit LDS.
// Fence-free memory-side protocol (r6-proven): unsafeAtomicAdd f32 into
// rotating S buffers, one block-flag per step, relaxed agent atomic loads.

constexpr int CB   = 256;   // batch
constexpr int CT   = 512;   // time steps
constexpr int DIN  = 128;
constexpr int DST  = 128;
constexpr int DOUT = 64;
constexpr int DAUG = 256;   // DIN + DST

constexpr int NBG = 16;     // batch groups
constexpr int NNG = 8;      // neuron groups (blocks per barrier group)
constexpr int BT  = 16;     // batch rows per group
constexpr int NT  = 256;    // neurons per block

constexpr int EPAD = 264;   // 256 + 8 bf16 pad
constexpr int APAD = 264;   // 256 + 8 bf16 pad (A is [b][n], n=256)

using f32x4  = __attribute__((ext_vector_type(4))) float;
using bf16x8 = __attribute__((ext_vector_type(8))) short;   // 8 bf16 in 4 VGPRs

__device__ __forceinline__ short f2b(float x) {   // f32 -> bf16 RNE
  unsigned u = __builtin_bit_cast(unsigned, x);
  u += 0x7fffu + ((u >> 16) & 1u);
  return (short)(u >> 16);
}
__device__ __forceinline__ short4 f2b4(float4 v) {
  return make_short4(f2b(v.x), f2b(v.y), f2b(v.z), f2b(v.w));
}

__global__ void nef_init(float* Sbuf, unsigned int* ctrs, float* out) {
  int idx = blockIdx.x * blockDim.x + threadIdx.x;
  int stride = gridDim.x * blockDim.x;
  for (int i = idx; i < 4 * CB * DST; i += stride) Sbuf[i] = 0.f;  // 4 state buffers
  for (int i = idx; i < CB * DOUT; i += stride) out[i] = 0.f;
  if (idx < 16 * 64) ctrs[idx] = 0u;                               // barrier ctrs
}

__global__ void __launch_bounds__(256) nef_main(
    const float* __restrict__ seq,  const float* __restrict__ enc,
    const float* __restrict__ gainp,const float* __restrict__ biasp,
    const float* __restrict__ sdec, const float* __restrict__ dec,
    float* __restrict__ out, float* __restrict__ Sbuf, unsigned int* ctrs)
{
  __shared__ short E_lds[NT][EPAD];     // encoders tile  [n][k_aug]   135.2 KB
  __shared__ short X_lds[BT][EPAD];     // [u_t | s_t]    [b][k_aug]     8.4 KB
  __shared__ short A_lds[BT][APAD];     // activations    [b][n]         8.4 KB
  __shared__ float gain_lds[NT];
  __shared__ float bias_lds[NT];

  const int tid  = threadIdx.x;
  const int bg   = blockIdx.x & 15;   // group's 8 blocks land on one XCD (perf only)
  const int ng   = blockIdx.x >> 4;
  const int b0   = bg * BT;
  const int n0   = ng * NT;
  const int wave = tid >> 6;
  const int lane = tid & 63;
  const int l15  = lane & 15;
  const int lhi  = lane >> 4;         // 0..3
  const int kbase = lhi * 8;

  // ---- one-time: stage encoders into LDS (bf16): 256 rows x 256 cols f32 ----
  for (int i = 0; i < 64; ++i) {
    int fidx = i * 256 + tid;
    int row = fidx >> 6, c4 = fidx & 63;
    const float4 v = *(const float4*)(enc + (size_t)(n0 + row) * DAUG + (c4 << 2));
    *(short4*)&E_lds[row][c4 << 2] = f2b4(v);
  }
  if (tid < NT) { gain_lds[tid] = gainp[n0 + tid]; bias_lds[tid] = biasp[n0 + tid]; }
  else if (tid < 2 * NT) { /* second half loads bias half */ }
  if (tid >= NT) { gain_lds[tid & 255] = gain_lds[tid & 255]; }   // no-op keep simple
  // (NT == 256 == blockDim, so the first branch covers all of gain/bias)

  // ---- one-time: gather state_decoders^T fragments into REGISTERS ----
  // GEMM B B-operand: wave w covers d-cols w*32+{0..15} (frag0) and +16 (frag1),
  // K = this block's 256 neurons in 8 chunks of 32.
  bf16x8 sdt0[8], sdt1[8];
#pragma unroll
  for (int kk = 0; kk < 8; ++kk) {
    bf16x8 f0, f1;
    const int dA = wave * 32 + l15, dB = dA + 16;
#pragma unroll
    for (int j = 0; j < 8; ++j) {
      const size_t nrow = (size_t)(n0 + kk * 32 + kbase + j) * DST;
      f0[j] = f2b(sdec[nrow + dA]);
      f1[j] = f2b(sdec[nrow + dB]);
    }
    sdt0[kk] = f0; sdt1[kk] = f1;
  }

  unsigned int* ctr = ctrs + bg * 64;   // one 256B-strided ctr per group
  const int nsub = wave * 64;           // wave's 64-neuron range in GEMM A

  // ---- prologue: load u_0, stage X u-half, prefetch u_1 ----
  float4 pu[2];
#pragma unroll
  for (int i = 0; i < 2; ++i) {
    int fidx = i * 256 + tid;
    int row = fidx >> 5, c4 = fidx & 31;
    pu[i] = *(const float4*)(seq + ((size_t)(b0 + row) * CT + 0) * DIN + (c4 << 2));
  }
#pragma unroll
  for (int i = 0; i < 2; ++i) {
    int fidx = i * 256 + tid;
    int row = fidx >> 5, c4 = fidx & 31;
    *(short4*)&X_lds[row][c4 << 2] = f2b4(pu[i]);
    pu[i] = *(const float4*)(seq + ((size_t)(b0 + row) * CT + 1) * DIN + (c4 << 2));
  }
  __syncthreads();   // weights + u_0 staged

  for (int t = 0; t < CT; ++t) {
    // ---- zero S[(t+2)&3] (fire-forget agent stores; drained by barrier(1)
    // below, well before this step's flag). Readers of that buffer ran at t-2
    // (we passed poll(t-1)); its next adders run at t+1 after our flag(t). ----
    {
      float* Sz = Sbuf + ((t + 2) & 3) * (CB * DST);
      __hip_atomic_store(&Sz[b0 * DST + ng * 256 + tid], 0.f,
                         __ATOMIC_RELAXED, __HIP_MEMORY_SCOPE_AGENT);
    }

    // ---- GEMM A u-half (kk 0..3): s-independent pre-poll work ----
    f32x4 acc0 = {0,0,0,0}, acc1 = {0,0,0,0}, acc2 = {0,0,0,0}, acc3 = {0,0,0,0};
#pragma unroll
    for (int kk = 0; kk < 4; ++kk) {
      bf16x8 a = *(const bf16x8*)&X_lds[l15][kk * 32 + kbase];
      bf16x8 e0 = *(const bf16x8*)&E_lds[nsub +      l15][kk * 32 + kbase];
      bf16x8 e1 = *(const bf16x8*)&E_lds[nsub + 16 + l15][kk * 32 + kbase];
      bf16x8 e2 = *(const bf16x8*)&E_lds[nsub + 32 + l15][kk * 32 + kbase];
      bf16x8 e3 = *(const bf16x8*)&E_lds[nsub + 48 + l15][kk * 32 + kbase];
      acc0 = __builtin_amdgcn_mfma_f32_16x16x32_bf16(a, e0, acc0, 0, 0, 0);
      acc1 = __builtin_amdgcn_mfma_f32_16x16x32_bf16(a, e1, acc1, 0, 0, 0);
      acc2 = __builtin_amdgcn_mfma_f32_16x16x32_bf16(a, e2, acc2, 0, 0, 0);
      acc3 = __builtin_amdgcn_mfma_f32_16x16x32_bf16(a, e3, acc3, 0, 0, 0);
    }

    // ---- wait for s_t: all 8 group blocks posted step t-1 adds ----
    if (t > 0) {
      unsigned int tgt = 8u * (unsigned)t, guard = 0;
      while (__hip_atomic_load(ctr, __ATOMIC_RELAXED, __HIP_MEMORY_SCOPE_AGENT) < tgt) {
        __builtin_amdgcn_s_sleep(1);
        if (++guard > 100000u) break;   // bounded: wrong answer, never a wedge
      }
    }
    // ---- stage s-half: S f32 (coherent LLC) -> bf16 LDS, 8B agent loads ----
    {
      const float* Sr = Sbuf + (t & 3) * (CB * DST);
      int row = tid >> 4, c8 = tid & 15;       // 16 rows x 16 chunks of 8 f32
      const unsigned long long* p =
          (const unsigned long long*)(Sr + (size_t)(b0 + row) * DST + c8 * 8);
      short s8[8];
#pragma unroll
      for (int q = 0; q < 4; ++q) {
        unsigned long long w = __hip_atomic_load(p + q, __ATOMIC_RELAXED,
                                                 __HIP_MEMORY_SCOPE_AGENT);
        s8[2 * q]     = f2b(__builtin_bit_cast(float, (unsigned)(w & 0xffffffffu)));
        s8[2 * q + 1] = f2b(__builtin_bit_cast(float, (unsigned)(w >> 32)));
      }
      *(short4*)&X_lds[row][DIN + c8 * 8]     = make_short4(s8[0], s8[1], s8[2], s8[3]);
      *(short4*)&X_lds[row][DIN + c8 * 8 + 4] = make_short4(s8[4], s8[5], s8[6], s8[7]);
    }
    __syncthreads();   // (1) s-half of X visible

    // ---- GEMM A s-half (kk 4..7) ----
#pragma unroll
    for (int kk = 4; kk < 8; ++kk) {
      bf16x8 a = *(const bf16x8*)&X_lds[l15][kk * 32 + kbase];
      bf16x8 e0 = *(const bf16x8*)&E_lds[nsub +      l15][kk * 32 + kbase];
      bf16x8 e1 = *(const bf16x8*)&E_lds[nsub + 16 + l15][kk * 32 + kbase];
      bf16x8 e2 = *(const bf16x8*)&E_lds[nsub + 32 + l15][kk * 32 + kbase];
      bf16x8 e3 = *(const bf16x8*)&E_lds[nsub + 48 + l15][kk * 32 + kbase];
      acc0 = __builtin_amdgcn_mfma_f32_16x16x32_bf16(a, e0, acc0, 0, 0, 0);
      acc1 = __builtin_amdgcn_mfma_f32_16x16x32_bf16(a, e1, acc1, 0, 0, 0);
      acc2 = __builtin_amdgcn_mfma_f32_16x16x32_bf16(a, e2, acc2, 0, 0, 0);
      acc3 = __builtin_amdgcn_mfma_f32_16x16x32_bf16(a, e3, acc3, 0, 0, 0);
    }
    {   // epilogue: relu(gain*x + bias) -> bf16 a-tile in LDS
      const int nc0 = nsub + l15, nc1 = nc0 + 16, nc2 = nc0 + 32, nc3 = nc0 + 48;
      const float g0 = gain_lds[nc0], bi0 = bias_lds[nc0];
      const float g1 = gain_lds[nc1], bi1 = bias_lds[nc1];
      const float g2 = gain_lds[nc2], bi2 = bias_lds[nc2];
      const float g3 = gain_lds[nc3], bi3 = bias_lds[nc3];
#pragma unroll
      for (int j = 0; j < 4; ++j) {   // C/D: col=lane&15, row=(lane>>4)*4+j
        A_lds[lhi * 4 + j][nc0] = f2b(fmaxf(g0 * acc0[j] + bi0, 0.f));
        A_lds[lhi * 4 + j][nc1] = f2b(fmaxf(g1 * acc1[j] + bi1, 0.f));
        A_lds[lhi * 4 + j][nc2] = f2b(fmaxf(g2 * acc2[j] + bi2, 0.f));
        A_lds[lhi * 4 + j][nc3] = f2b(fmaxf(g3 * acc3[j] + bi3, 0.f));
      }
    }
    __syncthreads();   // (2) A_lds ready; X free to overwrite

    if (t != CT - 1) {
      // ---- GEMM B: (16 x 256) @ (256 x 128) -> partial s_{t+1};
      //      B-operand from registers (sdt0/sdt1) ----
      f32x4 p0 = {0,0,0,0}, p1 = {0,0,0,0};
#pragma unroll
      for (int kk = 0; kk < 8; ++kk) {
        bf16x8 a = *(const bf16x8*)&A_lds[l15][kk * 32 + kbase];
        p0 = __builtin_amdgcn_mfma_f32_16x16x32_bf16(a, sdt0[kk], p0, 0, 0, 0);
        p1 = __builtin_amdgcn_mfma_f32_16x16x32_bf16(a, sdt1[kk], p1, 0, 0, 0);
      }
      // ---- memory-side f32 RMWs into S[(t+1)&3]: 8 per thread ----
      float* Sw = Sbuf + ((t + 1) & 3) * (CB * DST);
      const int dA = wave * 32 + l15, dB = dA + 16;
#pragma unroll
      for (int j = 0; j < 4; ++j) {
        unsafeAtomicAdd(&Sw[(size_t)(b0 + lhi * 4 + j) * DST + dA], p0[j]);
        unsafeAtomicAdd(&Sw[(size_t)(b0 + lhi * 4 + j) * DST + dB], p1[j]);
      }
      // ---- stage u_{t+1} into X u-half (LDS work overlaps the add drain) ----
#pragma unroll
      for (int i = 0; i < 2; ++i) {
        int fidx = i * 256 + tid;
        int row = fidx >> 5, c4 = fidx & 31;
        *(short4*)&X_lds[row][c4 << 2] = f2b4(pu[i]);
      }
      __syncthreads();   // (3) drains adds (vmcnt) + u-stage LDS writes
      if (tid == 0) atomicAdd(ctr, 1u);
      // ---- off-path: issue u_{t+2} prefetch (drains at next iter's use) ----
      if (t + 2 < CT) {
#pragma unroll
        for (int i = 0; i < 2; ++i) {
          int fidx = i * 256 + tid;
          int row = fidx >> 5, c4 = fidx & 31;
          pu[i] = *(const float4*)(seq + ((size_t)(b0 + row) * CT + (t + 2)) * DIN + (c4 << 2));
        }
      }
    } else {
      // ---- final step: out partial = a_final @ decoders[n0:n0+256] ----
      f32x4 o0 = {0,0,0,0};
      const int ocol = wave * 16 + l15;   // 4 waves x 16 = DOUT
#pragma unroll
      for (int kk = 0; kk < 8; ++kk) {
        bf16x8 a = *(const bf16x8*)&A_lds[l15][kk * 32 + kbase];
        bf16x8 bfD;
#pragma unroll
        for (int j = 0; j < 8; ++j)
          bfD[j] = f2b(dec[(size_t)(n0 + kk * 32 + kbase + j) * DOUT + ocol]);
        o0 = __builtin_amdgcn_mfma_f32_16x16x32_bf16(a, bfD, o0, 0, 0, 0);
      }
#pragma unroll
      for (int j = 0; j < 4; ++j)         // one-time 8-way K-split reduction
        unsafeAtomicAdd(&out[(size_t)(b0 + lhi * 4 + j) * DOUT + ocol], o0[j]);
    }
  }
}

extern "C" void kernel_launch(void* const* d_in, const int* in_sizes, int n_in,
                              void* d_out, int out_size, void* d_ws, size_t ws_size,
                              hipStream_t stream) {
  const float* seq   = (const float*)d_in[0];
  const float* enc   = (const float*)d_in[1];
  const float* gainp = (const float*)d_in[2];
  const float* biasp = (const float*)d_in[3];
  const float* sdec  = (const float*)d_in[4];
  const float* dec   = (const float*)d_in[5];
  float* out = (float*)d_out;

  // workspace: Sbuf f32 [4][256][128] = 512 KB | ctrs 16*64 u32 = 4 KB
  float* Sbuf = (float*)d_ws;
  unsigned int* ctrs = (unsigned int*)((char*)d_ws + (size_t)4 * CB * DST * sizeof(float));

  nef_init<<<128, 256, 0, stream>>>(Sbuf, ctrs, out);
  nef_main<<<dim3(NBG * NNG), dim3(256), 0, stream>>>(seq, enc, gainp, biasp,
                                                      sdec, dec, out, Sbuf, ctrs);
}